// Round 1
// baseline (4737.045 us; speedup 1.0000x reference)
//
#include <hip/hip_runtime.h>
#include <math.h>

#define T_STEPS 64
#define B_ENVS 128
#define L_TOK 64
#define E_DIM 256
#define H_DIM 32
#define N_SEQ (T_STEPS * B_ENVS)   // 8192
#define G4H 128                    // 4*H
#define PAD 65                     // LDS row pad: stride 65 words -> conflict-free column reads

// ---------------------------------------------------------------------------
// K0a: M[i][j] = (1/16) * sum_e Wq[e][i] * Wk[e][j]
//   Wq = in_proj_w rows [0,256), Wk = rows [256,512). in_proj_w is [768][256].
// ---------------------------------------------------------------------------
__global__ void k_precompute_M(const float* __restrict__ ipw, float* __restrict__ M) {
    const int i = blockIdx.x;    // 0..255
    const int j = threadIdx.x;   // 0..255
    float acc = 0.f;
    for (int e = 0; e < E_DIM; ++e) {
        acc = fmaf(ipw[e * E_DIM + i], ipw[(E_DIM + e) * E_DIM + j], acc);
    }
    M[i * E_DIM + j] = acc * (1.0f / 16.0f);   // 1/sqrt(E), E=256
}

// ---------------------------------------------------------------------------
// K0b: R[g][e] = sum_{e'} w_ih[g][e'] * Wo[e'][e]     (R = w_ih @ out_proj_w)
// ---------------------------------------------------------------------------
__global__ void k_precompute_R(const float* __restrict__ w_ih,
                               const float* __restrict__ opw,
                               float* __restrict__ R) {
    const int g = blockIdx.x;    // 0..127
    const int e = threadIdx.x;   // 0..255
    float acc = 0.f;
    for (int ep = 0; ep < E_DIM; ++ep) {
        acc = fmaf(w_ih[g * E_DIM + ep], opw[ep * E_DIM + e], acc);
    }
    R[g * E_DIM + e] = acc;
}

// ---------------------------------------------------------------------------
// K0c: Q[i][g] = sum_e Wv[e][i] * R[g][e]   (Wv = in_proj_w rows [512,768))
//   gates_x = ((w @ x) @ Wv^T @ Wo^T) @ w_ih^T = u @ Q
// ---------------------------------------------------------------------------
__global__ void k_precompute_Q(const float* __restrict__ ipw,
                               const float* __restrict__ R,
                               float* __restrict__ Q) {
    const int g = blockIdx.x;    // 0..127
    const int i = threadIdx.x;   // 0..255
    float acc = 0.f;
    for (int e = 0; e < E_DIM; ++e) {
        acc = fmaf(ipw[(2 * E_DIM + e) * E_DIM + i], R[g * E_DIM + e], acc);
    }
    Q[i * G4H + g] = acc;
}

// ---------------------------------------------------------------------------
// K1: per-sequence attention, fully fused:
//   y = x@M (chunked over e), scores += y_chunk @ x^T, mask+softmax,
//   w = colsum(probs), u = w@x, gates_x = u@Q
// One block per sequence n, 512 threads (8 waves).
// ---------------------------------------------------------------------------
__global__ __launch_bounds__(512) void k_attn(const float* __restrict__ x,
                                              const int* __restrict__ obs_mask,
                                              const float* __restrict__ M,
                                              const float* __restrict__ Q,
                                              float* __restrict__ gates_x) {
    __shared__ float y_t[64 * PAD];      // y chunk, TRANSPOSED: y_t[e_local][l]
    __shared__ float sc[64 * PAD];       // scores[a][b], padded
    __shared__ float dropped[64];        // 1.0 where obs_mask==0
    __shared__ float pcol[8][64];        // colsum partials per wave
    __shared__ float w_l[64];            // colsum weights
    __shared__ float upart[2][256];
    __shared__ float u_l[256];           // u = w @ x
    __shared__ float gpart[4][128];

    const int n = blockIdx.x;
    const int t = threadIdx.x;
    const float* xn = x + (size_t)n * (L_TOK * E_DIM);

    if (t < 64) dropped[t] = (obs_mask[n * L_TOK + t] == 0) ? 1.0f : 0.0f;

    // phase B tiling: thread covers e = ec + 4*te2 .. +3, rows l0, l0+1
    const int te2 = t & 15;
    const int tl2 = t >> 4;              // 0..31
    const int l0 = 2 * tl2;
    // phase C tiling: thread covers scores row a, cols 8*bg .. 8*bg+7
    const int a = t & 63;
    const int bg = t >> 6;               // 0..7 == wave id

    float accs[8];
#pragma unroll
    for (int j = 0; j < 8; ++j) accs[j] = 0.f;

    __syncthreads();   // dropped[] visible later; also orders LDS init

    for (int ec = 0; ec < E_DIM; ec += 64) {
        // ---- phase B: y[l][e] for e in [ec, ec+64) ----
        float acc0[4] = {0.f, 0.f, 0.f, 0.f};
        float acc1[4] = {0.f, 0.f, 0.f, 0.f};
        const int e0 = ec + 4 * te2;
        const float* xr0 = xn + l0 * E_DIM;
        const float* xr1 = xn + (l0 + 1) * E_DIM;
        for (int i0 = 0; i0 < E_DIM; i0 += 4) {
            const float4 xa = *(const float4*)(xr0 + i0);
            const float4 xb = *(const float4*)(xr1 + i0);
            const float* Mp = M + (size_t)i0 * E_DIM + e0;
            const float4 m0 = *(const float4*)(Mp);
            const float4 m1 = *(const float4*)(Mp + E_DIM);
            const float4 m2 = *(const float4*)(Mp + 2 * E_DIM);
            const float4 m3 = *(const float4*)(Mp + 3 * E_DIM);
            const float xav[4] = {xa.x, xa.y, xa.z, xa.w};
            const float xbv[4] = {xb.x, xb.y, xb.z, xb.w};
            const float4 mr[4] = {m0, m1, m2, m3};
#pragma unroll
            for (int ii = 0; ii < 4; ++ii) {
                const float* mm = (const float*)&mr[ii];
#pragma unroll
                for (int j = 0; j < 4; ++j) {
                    acc0[j] = fmaf(xav[ii], mm[j], acc0[j]);
                    acc1[j] = fmaf(xbv[ii], mm[j], acc1[j]);
                }
            }
        }
#pragma unroll
        for (int j = 0; j < 4; ++j) {
            y_t[(4 * te2 + j) * PAD + l0]     = acc0[j];
            y_t[(4 * te2 + j) * PAD + l0 + 1] = acc1[j];
        }
        __syncthreads();

        // ---- phase C: scores[a][b] += sum_{e in chunk} y[a][e] * x[b][e] ----
        for (int e2 = 0; e2 < 64; e2 += 4) {
            float yv[4];
#pragma unroll
            for (int j = 0; j < 4; ++j) yv[j] = y_t[(e2 + j) * PAD + a];
#pragma unroll
            for (int bj = 0; bj < 8; ++bj) {
                const float4 xv = *(const float4*)(xn + (8 * bg + bj) * E_DIM + ec + e2);
                accs[bj] = fmaf(yv[0], xv.x,
                           fmaf(yv[1], xv.y,
                           fmaf(yv[2], xv.z,
                           fmaf(yv[3], xv.w, accs[bj]))));
            }
        }
        __syncthreads();   // before overwriting y_t next chunk
    }

    // ---- write scores to LDS ----
#pragma unroll
    for (int j = 0; j < 8; ++j) sc[a * PAD + 8 * bg + j] = accs[j];
    __syncthreads();

    // ---- phase D: mask + softmax, per wave: rows 8*bg .. 8*bg+7, lane = a ----
    for (int r = 0; r < 8; ++r) {
        const int row = 8 * bg + r;
        float s = sc[row * PAD + a];
        const float da = dropped[row];
        const float db = dropped[a];
        if (da > 0.5f && db > 0.5f) s = -1e9f;   // blocked where BOTH dropped
        float mx = s;
#pragma unroll
        for (int off = 32; off; off >>= 1) mx = fmaxf(mx, __shfl_xor(mx, off));
        const float p = __expf(s - mx);
        float ssum = p;
#pragma unroll
        for (int off = 32; off; off >>= 1) ssum += __shfl_xor(ssum, off);
        sc[row * PAD + a] = p / ssum;
    }
    __syncthreads();

    // ---- colsum: w[b] = sum_a probs[a][b] ----
    {
        float partial = 0.f;
#pragma unroll
        for (int r = 0; r < 8; ++r) partial += sc[(8 * bg + r) * PAD + a];
        pcol[bg][a] = partial;
    }
    __syncthreads();
    if (t < 64) {
        float ws = 0.f;
#pragma unroll
        for (int k = 0; k < 8; ++k) ws += pcol[k][t];
        w_l[t] = ws;
    }
    __syncthreads();

    // ---- phase E: u[i] = sum_k w[k] * x[k][i] ----
    {
        const int i = t & 255;
        const int h2 = t >> 8;   // 0 or 1
        float acc = 0.f;
        for (int k = 32 * h2; k < 32 * h2 + 32; ++k) {
            acc = fmaf(w_l[k], xn[k * E_DIM + i], acc);
        }
        upart[h2][i] = acc;
    }
    __syncthreads();
    if (t < 256) u_l[t] = upart[0][t] + upart[1][t];
    __syncthreads();

    // ---- phase F: gates_x[n][g] = sum_i u[i] * Q[i][g] ----
    {
        const int g = t & 127;
        const int q = t >> 7;    // 0..3
        float acc = 0.f;
        for (int i = 64 * q; i < 64 * q + 64; ++i) {
            acc = fmaf(u_l[i], Q[i * G4H + g], acc);
        }
        gpart[q][g] = acc;
    }
    __syncthreads();
    if (t < 128) {
        const float gx = gpart[0][t] + gpart[1][t] + gpart[2][t] + gpart[3][t];
        gates_x[(size_t)n * G4H + t] = gx;
    }
}

// ---------------------------------------------------------------------------
// K2: per-env LSTM over T steps + fused critic head.
// One block per env b (128 blocks), 128 threads (one per gate output).
// ---------------------------------------------------------------------------
__device__ __forceinline__ float sigmoidf_(float v) {
    return 1.0f / (1.0f + __expf(-v));
}
__device__ __forceinline__ float tanh_safe(float v) {
    const float av = fabsf(v);
    const float e = __expf(-2.0f * av);       // in (0,1], no overflow
    const float r = (1.0f - e) / (1.0f + e);
    return v < 0.f ? -r : r;
}

__global__ __launch_bounds__(128) void k_lstm(const float* __restrict__ gates_x,
                                              const float* __restrict__ done,
                                              const float* __restrict__ h0,
                                              const float* __restrict__ c0,
                                              const float* __restrict__ w_hh,
                                              const float* __restrict__ b_ih,
                                              const float* __restrict__ b_hh,
                                              const float* __restrict__ critic_w,
                                              const float* __restrict__ critic_b,
                                              float* __restrict__ out) {
    __shared__ float h_l[H_DIM];
    __shared__ float gates_l[G4H];
    const int b = blockIdx.x;
    const int g = threadIdx.x;   // 0..127

    float wrow[H_DIM];
#pragma unroll
    for (int k = 0; k < H_DIM; ++k) wrow[k] = w_hh[g * H_DIM + k];
    const float bsum = b_ih[g] + b_hh[g];

    float c_reg = 0.f, cw = 0.f;
    if (g < H_DIM) {
        h_l[g] = h0[b * H_DIM + g];
        c_reg = c0[b * H_DIM + g];
        cw = critic_w[g];
    }
    const float cb = critic_b[0];
    __syncthreads();

    for (int step = 0; step < T_STEPS; ++step) {
        const int nidx = step * B_ENVS + b;
        const float keep = 1.0f - done[nidx];

        float dot = 0.f;
#pragma unroll
        for (int k = 0; k < H_DIM; ++k) dot = fmaf(h_l[k], wrow[k], dot);
        const float pre = gates_x[(size_t)nidx * G4H + g] + bsum + keep * dot;

        float v;
        if (g < 64)       v = sigmoidf_(pre);   // i, f gates
        else if (g < 96)  v = tanh_safe(pre);   // g gate
        else              v = sigmoidf_(pre);   // o gate
        gates_l[g] = v;
        __syncthreads();

        if (g < H_DIM) {
            const float iv = gates_l[g];
            const float fv = gates_l[H_DIM + g];
            const float gv = gates_l[2 * H_DIM + g];
            const float ov = gates_l[3 * H_DIM + g];
            c_reg = fmaf(fv, keep * c_reg, iv * gv);
            const float h = ov * tanh_safe(c_reg);
            h_l[g] = h;
            float val = h * cw;
#pragma unroll
            for (int off = 16; off; off >>= 1) val += __shfl_xor(val, off);
            if (g == 0) out[nidx] = val + cb;
        }
        __syncthreads();   // protect h_l against next-iteration reads
    }
}

// ---------------------------------------------------------------------------
extern "C" void kernel_launch(void* const* d_in, const int* in_sizes, int n_in,
                              void* d_out, int out_size, void* d_ws, size_t ws_size,
                              hipStream_t stream) {
    const float* x    = (const float*)d_in[0];
    const float* done = (const float*)d_in[1];
    const int* mask   = (const int*)d_in[2];
    const float* h0   = (const float*)d_in[3];
    const float* c0   = (const float*)d_in[4];
    const float* ipw  = (const float*)d_in[5];
    const float* opw  = (const float*)d_in[6];
    const float* w_ih = (const float*)d_in[7];
    const float* w_hh = (const float*)d_in[8];
    const float* b_ih = (const float*)d_in[9];
    const float* b_hh = (const float*)d_in[10];
    const float* cw   = (const float*)d_in[11];
    const float* cb   = (const float*)d_in[12];
    float* out = (float*)d_out;

    char* ws = (char*)d_ws;
    float* M  = (float*)(ws);                       // 256*256*4 = 256 KB
    float* R  = (float*)(ws + (256 * 1024));        // 128*256*4 = 128 KB
    float* Q  = (float*)(ws + (384 * 1024));        // 256*128*4 = 128 KB
    float* gx = (float*)(ws + (512 * 1024));        // 8192*128*4 = 4 MB

    k_precompute_M<<<256, 256, 0, stream>>>(ipw, M);
    k_precompute_R<<<128, 256, 0, stream>>>(w_ih, opw, R);
    k_precompute_Q<<<128, 256, 0, stream>>>(ipw, R, Q);
    k_attn<<<N_SEQ, 512, 0, stream>>>(x, mask, M, Q, gx);
    k_lstm<<<B_ENVS, 128, 0, stream>>>(gx, done, h0, c0, w_hh, b_ih, b_hh, cw, cb, out);
}

// Round 2
// 1423.183 us; speedup vs baseline: 3.3285x; 3.3285x over previous
//
#include <hip/hip_runtime.h>
#include <math.h>

#define T_STEPS 64
#define B_ENVS 128
#define L_TOK 64
#define E_DIM 256
#define H_DIM 32
#define N_SEQ (T_STEPS * B_ENVS)   // 8192
#define G4H 128                    // 4*H

// LDS bf16 tile row stride: 264 elems = 528 B = 132 words; 132 % 32 = 4 ->
// b128 frag reads spread across bank groups (8 lanes per 4-bank group = the
// b128 minimum), no extra conflicts.
#define BSTRIDE 264

typedef __bf16 bf16x8 __attribute__((ext_vector_type(8)));
typedef __bf16 bf16x4 __attribute__((ext_vector_type(4)));
typedef float f32x4 __attribute__((ext_vector_type(4)));

// ---------------------------------------------------------------------------
// K0a: Mtb[f][e] = bf16( (1/16) * sum_c ipw[c][e] * ipw[E+c][f] )  (= M[e][f])
//   scores = x @ M @ x^T. Stored TRANSPOSED so MFMA B-frags read rows.
// ---------------------------------------------------------------------------
__global__ void k_precompute_M(const float* __restrict__ ipw, __bf16* __restrict__ Mtb) {
    const int e = blockIdx.x;    // 0..255
    const int f = threadIdx.x;   // 0..255
    float acc = 0.f;
    for (int c = 0; c < E_DIM; ++c) {
        acc = fmaf(ipw[c * E_DIM + e], ipw[(E_DIM + c) * E_DIM + f], acc);
    }
    Mtb[f * E_DIM + e] = (__bf16)(acc * (1.0f / 16.0f));
}

// ---------------------------------------------------------------------------
// K0b: R[g][e] = sum_{e'} w_ih[g][e'] * Wo[e'][e]
// ---------------------------------------------------------------------------
__global__ void k_precompute_R(const float* __restrict__ w_ih,
                               const float* __restrict__ opw,
                               float* __restrict__ R) {
    const int g = blockIdx.x;    // 0..127
    const int e = threadIdx.x;   // 0..255
    float acc = 0.f;
    for (int ep = 0; ep < E_DIM; ++ep) {
        acc = fmaf(w_ih[g * E_DIM + ep], opw[ep * E_DIM + e], acc);
    }
    R[g * E_DIM + e] = acc;
}

// ---------------------------------------------------------------------------
// K0c: Q[i][g] = sum_e Wv[e][i] * R[g][e]   (Wv = in_proj_w rows [512,768))
// ---------------------------------------------------------------------------
__global__ void k_precompute_Q(const float* __restrict__ ipw,
                               const float* __restrict__ R,
                               float* __restrict__ Q) {
    const int g = blockIdx.x;    // 0..127
    const int i = threadIdx.x;   // 0..255
    float acc = 0.f;
    for (int e = 0; e < E_DIM; ++e) {
        acc = fmaf(ipw[(2 * E_DIM + e) * E_DIM + i], R[g * E_DIM + e], acc);
    }
    Q[i * G4H + g] = acc;
}

// ---------------------------------------------------------------------------
// K1: per-sequence fused attention via bf16 MFMA.
//   xb = bf16(x_n) in LDS; y = xb @ M (MFMA, wave owns 64 cols);
//   yb = bf16(y) in LDS; scores = yb @ xb^T (MFMA); in-register softmax;
//   w = colsum(probs); u = w @ xb; gates_x = u @ Q.
// 256 threads (4 waves) per block, 8192 blocks.
// ---------------------------------------------------------------------------
__global__ __launch_bounds__(256) void k_attn(const float* __restrict__ x,
                                              const int* __restrict__ obs_mask,
                                              const __bf16* __restrict__ Mtb,
                                              const float* __restrict__ Q,
                                              float* __restrict__ gates_x) {
    __shared__ __align__(16) __bf16 xb[L_TOK * BSTRIDE];   // 33792 B
    __shared__ __align__(16) __bf16 yb[L_TOK * BSTRIDE];   // 33792 B
    __shared__ float dropped[64];
    __shared__ float pcol[4][64];
    __shared__ float w_l[64];
    __shared__ float u_l[256];
    __shared__ float gpart[2][128];

    const int n = blockIdx.x;
    const int t = threadIdx.x;
    const int lane = t & 63;
    const int w = t >> 6;            // wave id 0..3
    const int lane15 = lane & 15;
    const int quad = lane >> 4;      // 0..3
    const float* xn = x + (size_t)n * (L_TOK * E_DIM);

    if (t < 64) dropped[t] = (obs_mask[n * L_TOK + t] == 0) ? 1.0f : 0.0f;

    // ---- stage x -> bf16 LDS (coalesced float4 reads, bf16x4 writes) ----
    {
        const float4* x4 = (const float4*)xn;
#pragma unroll
        for (int it = 0; it < 16; ++it) {
            const int flat4 = t + 256 * it;          // float4 index
            const int row = flat4 >> 6;              // /64 (64 float4 per row)
            const int col = (flat4 & 63) * 4;
            const float4 v = x4[flat4];
            bf16x4 pk;
            pk.x = (__bf16)v.x; pk.y = (__bf16)v.y;
            pk.z = (__bf16)v.z; pk.w = (__bf16)v.w;
            *(bf16x4*)&xb[row * BSTRIDE + col] = pk;
        }
    }
    __syncthreads();

    // ---- GEMM1: y = xb @ M ; wave w computes y[:, 64w .. 64w+63] ----
    // A-frag: xb[16rt + lane15][kc*32 + quad*8 ..+7]
    // B-frag: Mtb row (64w + 16ct + lane15), same k slice (global, L2-hot)
    f32x4 acc1[4][4];
#pragma unroll
    for (int rt = 0; rt < 4; ++rt)
#pragma unroll
        for (int ct = 0; ct < 4; ++ct) acc1[rt][ct] = (f32x4)0.f;

    for (int kc = 0; kc < 8; ++kc) {
        const int kofs = kc * 32 + quad * 8;
        bf16x8 afrag[4];
#pragma unroll
        for (int rt = 0; rt < 4; ++rt)
            afrag[rt] = *(const bf16x8*)&xb[(16 * rt + lane15) * BSTRIDE + kofs];
#pragma unroll
        for (int ct = 0; ct < 4; ++ct) {
            const bf16x8 bfrag =
                *(const bf16x8*)(Mtb + (size_t)(64 * w + 16 * ct + lane15) * E_DIM + kofs);
#pragma unroll
            for (int rt = 0; rt < 4; ++rt)
                acc1[rt][ct] = __builtin_amdgcn_mfma_f32_16x16x32_bf16(
                    afrag[rt], bfrag, acc1[rt][ct], 0, 0, 0);
        }
    }
    // write y -> yb (bf16). C-layout: row = 16rt + 4*quad + r, col = 64w+16ct+lane15
#pragma unroll
    for (int rt = 0; rt < 4; ++rt)
#pragma unroll
        for (int ct = 0; ct < 4; ++ct) {
            const int col = 64 * w + 16 * ct + lane15;
#pragma unroll
            for (int r = 0; r < 4; ++r)
                yb[(16 * rt + 4 * quad + r) * BSTRIDE + col] = (__bf16)acc1[rt][ct][r];
        }
    __syncthreads();

    // ---- GEMM2: scores = yb @ xb^T ; wave w computes rows 16w..16w+15 ----
    f32x4 acc2[4];
#pragma unroll
    for (int ct = 0; ct < 4; ++ct) acc2[ct] = (f32x4)0.f;
    for (int kc = 0; kc < 8; ++kc) {
        const int kofs = kc * 32 + quad * 8;
        const bf16x8 a2 = *(const bf16x8*)&yb[(16 * w + lane15) * BSTRIDE + kofs];
#pragma unroll
        for (int ct = 0; ct < 4; ++ct) {
            const bf16x8 b2 = *(const bf16x8*)&xb[(16 * ct + lane15) * BSTRIDE + kofs];
            acc2[ct] = __builtin_amdgcn_mfma_f32_16x16x32_bf16(a2, b2, acc2[ct], 0, 0, 0);
        }
    }

    // ---- mask + softmax in C-layout: row = 16w + 4*quad + r, col = 16ct+lane15 ----
    float db[4];
#pragma unroll
    for (int ct = 0; ct < 4; ++ct) db[ct] = dropped[16 * ct + lane15];
    float colpart[4] = {0.f, 0.f, 0.f, 0.f};
#pragma unroll
    for (int r = 0; r < 4; ++r) {
        const float da = dropped[16 * w + 4 * quad + r];
        float s[4];
#pragma unroll
        for (int ct = 0; ct < 4; ++ct) {
            s[ct] = acc2[ct][r];
            if (da > 0.5f && db[ct] > 0.5f) s[ct] = -1e9f;
        }
        float mx = fmaxf(fmaxf(s[0], s[1]), fmaxf(s[2], s[3]));
#pragma unroll
        for (int off = 1; off < 16; off <<= 1) mx = fmaxf(mx, __shfl_xor(mx, off));
        float p[4], ssum = 0.f;
#pragma unroll
        for (int ct = 0; ct < 4; ++ct) { p[ct] = __expf(s[ct] - mx); ssum += p[ct]; }
#pragma unroll
        for (int off = 1; off < 16; off <<= 1) ssum += __shfl_xor(ssum, off);
        const float inv = 1.0f / ssum;
#pragma unroll
        for (int ct = 0; ct < 4; ++ct) colpart[ct] = fmaf(p[ct], inv, colpart[ct]);
    }
    // colpart[ct] = sum over this quad's 4 rows; reduce across quads (xor 16,32)
#pragma unroll
    for (int ct = 0; ct < 4; ++ct) {
        float cp = colpart[ct];
        cp += __shfl_xor(cp, 16);
        cp += __shfl_xor(cp, 32);
        colpart[ct] = cp;
    }
    if (quad == 0) {
#pragma unroll
        for (int ct = 0; ct < 4; ++ct) pcol[w][16 * ct + lane15] = colpart[ct];
    }
    __syncthreads();
    if (t < 64) w_l[t] = pcol[0][t] + pcol[1][t] + pcol[2][t] + pcol[3][t];
    __syncthreads();

    // ---- phase E: u[i] = sum_k w[k] * xb[k][i] ----
    {
        float acc = 0.f;
#pragma unroll 8
        for (int k = 0; k < 64; ++k)
            acc = fmaf(w_l[k], (float)xb[k * BSTRIDE + t], acc);
        u_l[t] = acc;
    }
    __syncthreads();

    // ---- phase F: gates_x[n][g] = sum_i u[i] * Q[i][g] ----
    {
        const int g = t & 127;
        const int q = t >> 7;    // 0..1
        float acc = 0.f;
        for (int i = 128 * q; i < 128 * q + 128; ++i)
            acc = fmaf(u_l[i], Q[i * G4H + g], acc);
        gpart[q][g] = acc;
    }
    __syncthreads();
    if (t < 128)
        gates_x[(size_t)n * G4H + t] = gpart[0][t] + gpart[1][t];
}

// ---------------------------------------------------------------------------
// K2: per-env LSTM over T steps + fused critic head.
// ONE WAVE per env (64 threads, 128 blocks): lane l owns gates l and 64+l.
// Gate exchange via shuffles; h via LDS (single wave -> one barrier/step).
// ---------------------------------------------------------------------------
__device__ __forceinline__ float sigmoidf_(float v) {
    return 1.0f / (1.0f + __expf(-v));
}
__device__ __forceinline__ float tanh_safe(float v) {
    const float av = fabsf(v);
    const float e = __expf(-2.0f * av);
    const float r = (1.0f - e) / (1.0f + e);
    return v < 0.f ? -r : r;
}

__global__ __launch_bounds__(64) void k_lstm(const float* __restrict__ gates_x,
                                             const float* __restrict__ done,
                                             const float* __restrict__ h0,
                                             const float* __restrict__ c0,
                                             const float* __restrict__ w_hh,
                                             const float* __restrict__ b_ih,
                                             const float* __restrict__ b_hh,
                                             const float* __restrict__ critic_w,
                                             const float* __restrict__ critic_b,
                                             float* __restrict__ out) {
    __shared__ float h_l[H_DIM];
    const int b = blockIdx.x;
    const int l = threadIdx.x;        // 0..63
    const int g0 = l;                 // i (l<32) / f (l>=32) gate
    const int g1 = 64 + l;            // g (l<32) / o (l>=32) gate

    float wr0[H_DIM], wr1[H_DIM];
#pragma unroll
    for (int k = 0; k < H_DIM; ++k) {
        wr0[k] = w_hh[g0 * H_DIM + k];
        wr1[k] = w_hh[g1 * H_DIM + k];
    }
    const float bs0 = b_ih[g0] + b_hh[g0];
    const float bs1 = b_ih[g1] + b_hh[g1];

    float c_reg = 0.f, cw = 0.f;
    if (l < H_DIM) {
        h_l[l] = h0[b * H_DIM + l];
        c_reg = c0[b * H_DIM + l];
        cw = critic_w[l];
    }
    const float cb = critic_b[0];
    __syncthreads();

    for (int step = 0; step < T_STEPS; ++step) {
        const int nidx = step * B_ENVS + b;
        const float keep = 1.0f - done[nidx];

        float d0 = 0.f, d1 = 0.f;
#pragma unroll
        for (int k = 0; k < H_DIM; ++k) {
            const float hk = h_l[k];
            d0 = fmaf(hk, wr0[k], d0);
            d1 = fmaf(hk, wr1[k], d1);
        }
        const float pre0 = gates_x[(size_t)nidx * G4H + g0] + bs0 + keep * d0;
        const float pre1 = gates_x[(size_t)nidx * G4H + g1] + bs1 + keep * d1;

        const float act0 = sigmoidf_(pre0);                       // i or f
        const float act1 = (l < 32) ? tanh_safe(pre1)             // g
                                    : sigmoidf_(pre1);            // o
        const float fv = __shfl_xor(act0, 32);   // lane j<32 gets f_j
        const float ov = __shfl_xor(act1, 32);   // lane j<32 gets o_j
        __syncthreads();  // h_l reads done before overwrite

        if (l < H_DIM) {
            c_reg = fmaf(fv, keep * c_reg, act0 * act1);   // f*(keep*c) + i*g
            const float h = ov * tanh_safe(c_reg);
            h_l[l] = h;
            float val = h * cw;
#pragma unroll
            for (int off = 1; off < 32; off <<= 1) val += __shfl_xor(val, off);
            if (l == 0) out[nidx] = val + cb;
        }
        __syncthreads();  // h_l writes visible to next step's dot
    }
}

// ---------------------------------------------------------------------------
extern "C" void kernel_launch(void* const* d_in, const int* in_sizes, int n_in,
                              void* d_out, int out_size, void* d_ws, size_t ws_size,
                              hipStream_t stream) {
    const float* x    = (const float*)d_in[0];
    const float* done = (const float*)d_in[1];
    const int* mask   = (const int*)d_in[2];
    const float* h0   = (const float*)d_in[3];
    const float* c0   = (const float*)d_in[4];
    const float* ipw  = (const float*)d_in[5];
    const float* opw  = (const float*)d_in[6];
    const float* w_ih = (const float*)d_in[7];
    const float* w_hh = (const float*)d_in[8];
    const float* b_ih = (const float*)d_in[9];
    const float* b_hh = (const float*)d_in[10];
    const float* cw   = (const float*)d_in[11];
    const float* cb   = (const float*)d_in[12];
    float* out = (float*)d_out;

    char* ws = (char*)d_ws;
    __bf16* Mtb = (__bf16*)(ws);                    // 256*256*2 = 128 KB
    float* R    = (float*)(ws + (128 * 1024));      // 128*256*4 = 128 KB
    float* Q    = (float*)(ws + (256 * 1024));      // 256*128*4 = 128 KB
    float* gx   = (float*)(ws + (384 * 1024));      // 8192*128*4 = 4 MB

    k_precompute_M<<<256, 256, 0, stream>>>(ipw, Mtb);
    k_precompute_R<<<128, 256, 0, stream>>>(w_ih, opw, R);
    k_precompute_Q<<<128, 256, 0, stream>>>(ipw, R, Q);
    k_attn<<<N_SEQ, 256, 0, stream>>>(x, mask, Mtb, Q, gx);
    k_lstm<<<B_ENVS, 64, 0, stream>>>(gx, done, h0, c0, w_hh, b_ih, b_hh, cw, cb, out);
}

// Round 3
// 915.674 us; speedup vs baseline: 5.1733x; 1.5542x over previous
//
#include <hip/hip_runtime.h>
#include <math.h>

#define T_STEPS 64
#define B_ENVS 128
#define L_TOK 64
#define E_DIM 256
#define H_DIM 32
#define N_SEQ (T_STEPS * B_ENVS)   // 8192
#define G4H 128                    // 4*H

// LDS bf16 tile row stride: 264 elems = 132 words; 132 % 32 = 4 -> b128 frag
// reads across 16 rows land 2-way per bank (free, m136).
#define BSTRIDE 264

typedef __bf16 bf16x8 __attribute__((ext_vector_type(8)));
typedef __bf16 bf16x4 __attribute__((ext_vector_type(4)));
typedef float f32x4 __attribute__((ext_vector_type(4)));

// ---------------------------------------------------------------------------
// K0a: Mtb[f][e] = bf16( (1/16) * sum_c ipw[c][e] * ipw[E+c][f] )  (= M[e][f])
// ---------------------------------------------------------------------------
__global__ void k_precompute_M(const float* __restrict__ ipw, __bf16* __restrict__ Mtb) {
    const int e = blockIdx.x;
    const int f = threadIdx.x;
    float acc = 0.f;
    for (int c = 0; c < E_DIM; ++c) {
        acc = fmaf(ipw[c * E_DIM + e], ipw[(E_DIM + c) * E_DIM + f], acc);
    }
    Mtb[f * E_DIM + e] = (__bf16)(acc * (1.0f / 16.0f));
}

// ---------------------------------------------------------------------------
// K0b: R[g][e] = sum_{e'} w_ih[g][e'] * Wo[e'][e]
// ---------------------------------------------------------------------------
__global__ void k_precompute_R(const float* __restrict__ w_ih,
                               const float* __restrict__ opw,
                               float* __restrict__ R) {
    const int g = blockIdx.x;
    const int e = threadIdx.x;
    float acc = 0.f;
    for (int ep = 0; ep < E_DIM; ++ep) {
        acc = fmaf(w_ih[g * E_DIM + ep], opw[ep * E_DIM + e], acc);
    }
    R[g * E_DIM + e] = acc;
}

// ---------------------------------------------------------------------------
// K0c: Q[i][g] = sum_e Wv[e][i] * R[g][e]
// ---------------------------------------------------------------------------
__global__ void k_precompute_Q(const float* __restrict__ ipw,
                               const float* __restrict__ R,
                               float* __restrict__ Q) {
    const int g = blockIdx.x;
    const int i = threadIdx.x;
    float acc = 0.f;
    for (int e = 0; e < E_DIM; ++e) {
        acc = fmaf(ipw[(2 * E_DIM + e) * E_DIM + i], R[g * E_DIM + e], acc);
    }
    Q[i * G4H + g] = acc;
}

// ---------------------------------------------------------------------------
// K1: per-sequence fused attention. 1024 threads (16 waves), 2 blocks/CU.
//   Wave w computes y cols 16w..16w+15 in GEMM1 (32 MFMA, 16 acc VGPRs).
//   Waves 0-3 do GEMM2 + softmax + colsum. Phases E/F over all 1024 threads.
//   LDS: xb + yb (E/F scratch overlaid on yb) ~= 69 KB -> 2 blocks/CU.
// ---------------------------------------------------------------------------
__global__ __launch_bounds__(1024, 8) void k_attn(const float* __restrict__ x,
                                                  const int* __restrict__ obs_mask,
                                                  const __bf16* __restrict__ Mtb,
                                                  const float* __restrict__ Q,
                                                  float* __restrict__ gates_x) {
    __shared__ __align__(16) __bf16 xb[L_TOK * BSTRIDE];    // 33792 B
    __shared__ __align__(16) __bf16 ybuf[L_TOK * BSTRIDE];  // 33792 B (reused for E/F)
    __shared__ float dropped[64];
    __shared__ float pcol[4][64];

    // Overlays on ybuf (safe: two barriers separate last yb read from first write)
    float* upart = (float*)ybuf;           // [4][256] = 4096 B
    float* u_l   = (float*)ybuf + 1024;    // [256]    = 1024 B
    float* gpart = (float*)ybuf + 1280;    // [8][128] = 4096 B

    const int n = blockIdx.x;
    const int t = threadIdx.x;
    const int lane = t & 63;
    const int w = t >> 6;            // wave id 0..15
    const int lane15 = lane & 15;
    const int quad = lane >> 4;      // 0..3
    const float* xn = x + (size_t)n * (L_TOK * E_DIM);

    if (t < 64) dropped[t] = (obs_mask[n * L_TOK + t] == 0) ? 1.0f : 0.0f;

    // ---- stage x -> bf16 LDS (coalesced float4 reads) ----
    {
        const float4* x4 = (const float4*)xn;
#pragma unroll
        for (int it = 0; it < 4; ++it) {
            const int flat4 = t + 1024 * it;
            const int row = flat4 >> 6;
            const int col = (flat4 & 63) * 4;
            const float4 v = x4[flat4];
            bf16x4 pk;
            pk.x = (__bf16)v.x; pk.y = (__bf16)v.y;
            pk.z = (__bf16)v.z; pk.w = (__bf16)v.w;
            *(bf16x4*)&xb[row * BSTRIDE + col] = pk;
        }
    }
    __syncthreads();                                           // B1

    // ---- GEMM1: y = xb @ M ; wave w -> y[:, 16w..16w+15] ----
    {
        f32x4 acc1[4];
#pragma unroll
        for (int rt = 0; rt < 4; ++rt) acc1[rt] = (f32x4)0.f;

        const __bf16* mrow = Mtb + (size_t)(16 * w + lane15) * E_DIM;
#pragma unroll
        for (int kc = 0; kc < 8; ++kc) {
            const int kofs = kc * 32 + quad * 8;
            const bf16x8 bfrag = *(const bf16x8*)(mrow + kofs);
#pragma unroll
            for (int rt = 0; rt < 4; ++rt) {
                const bf16x8 afrag = *(const bf16x8*)&xb[(16 * rt + lane15) * BSTRIDE + kofs];
                acc1[rt] = __builtin_amdgcn_mfma_f32_16x16x32_bf16(afrag, bfrag, acc1[rt], 0, 0, 0);
            }
        }
        // C-layout: row = 16rt + 4*quad + r, col = 16w + lane15
#pragma unroll
        for (int rt = 0; rt < 4; ++rt) {
            const int col = 16 * w + lane15;
#pragma unroll
            for (int r = 0; r < 4; ++r)
                ybuf[(16 * rt + 4 * quad + r) * BSTRIDE + col] = (__bf16)acc1[rt][r];
        }
    }
    __syncthreads();                                           // B2

    // ---- GEMM2 + softmax + colsum: waves 0..3 only ----
    if (w < 4) {
        f32x4 acc2[4];
#pragma unroll
        for (int ct = 0; ct < 4; ++ct) acc2[ct] = (f32x4)0.f;
#pragma unroll
        for (int kc = 0; kc < 8; ++kc) {
            const int kofs = kc * 32 + quad * 8;
            const bf16x8 a2 = *(const bf16x8*)&ybuf[(16 * w + lane15) * BSTRIDE + kofs];
#pragma unroll
            for (int ct = 0; ct < 4; ++ct) {
                const bf16x8 b2 = *(const bf16x8*)&xb[(16 * ct + lane15) * BSTRIDE + kofs];
                acc2[ct] = __builtin_amdgcn_mfma_f32_16x16x32_bf16(a2, b2, acc2[ct], 0, 0, 0);
            }
        }
        float db[4];
#pragma unroll
        for (int ct = 0; ct < 4; ++ct) db[ct] = dropped[16 * ct + lane15];
        float colpart[4] = {0.f, 0.f, 0.f, 0.f};
#pragma unroll
        for (int r = 0; r < 4; ++r) {
            const float da = dropped[16 * w + 4 * quad + r];
            float s[4];
#pragma unroll
            for (int ct = 0; ct < 4; ++ct) {
                s[ct] = acc2[ct][r];
                if (da > 0.5f && db[ct] > 0.5f) s[ct] = -1e9f;
            }
            float mx = fmaxf(fmaxf(s[0], s[1]), fmaxf(s[2], s[3]));
#pragma unroll
            for (int off = 1; off < 16; off <<= 1) mx = fmaxf(mx, __shfl_xor(mx, off));
            float p[4], ssum = 0.f;
#pragma unroll
            for (int ct = 0; ct < 4; ++ct) { p[ct] = __expf(s[ct] - mx); ssum += p[ct]; }
#pragma unroll
            for (int off = 1; off < 16; off <<= 1) ssum += __shfl_xor(ssum, off);
            const float inv = 1.0f / ssum;
#pragma unroll
            for (int ct = 0; ct < 4; ++ct) colpart[ct] = fmaf(p[ct], inv, colpart[ct]);
        }
#pragma unroll
        for (int ct = 0; ct < 4; ++ct) {
            float cp = colpart[ct];
            cp += __shfl_xor(cp, 16);
            cp += __shfl_xor(cp, 32);
            colpart[ct] = cp;
        }
        if (quad == 0) {
#pragma unroll
            for (int ct = 0; ct < 4; ++ct) pcol[w][16 * ct + lane15] = colpart[ct];
        }
    }
    __syncthreads();                                           // B3

    // ---- phase E: u[i] = sum_k w[k] * xb[k][i]  (w inlined from pcol) ----
    {
        const int i = t & 255;
        const int kg = t >> 8;       // 0..3
        float acc = 0.f;
#pragma unroll
        for (int k = 16 * kg; k < 16 * kg + 16; ++k) {
            const float wk = pcol[0][k] + pcol[1][k] + pcol[2][k] + pcol[3][k];
            acc = fmaf(wk, (float)xb[k * BSTRIDE + i], acc);
        }
        upart[kg * 256 + i] = acc;
    }
    __syncthreads();                                           // B4
    if (t < 256)
        u_l[t] = upart[t] + upart[256 + t] + upart[512 + t] + upart[768 + t];
    __syncthreads();                                           // B5

    // ---- phase F: gates_x[n][g] = sum_i u[i] * Q[i][g] ----
    {
        const int g = t & 127;
        const int q = t >> 7;        // 0..7
        float acc = 0.f;
#pragma unroll
        for (int i = 32 * q; i < 32 * q + 32; ++i)
            acc = fmaf(u_l[i], Q[i * G4H + g], acc);
        gpart[q * 128 + g] = acc;
    }
    __syncthreads();                                           // B6
    if (t < 128) {
        float gx = 0.f;
#pragma unroll
        for (int q = 0; q < 8; ++q) gx += gpart[q * 128 + t];
        gates_x[(size_t)n * G4H + t] = gx;
    }
}

// ---------------------------------------------------------------------------
// K2: per-env LSTM, ONE WAVE per env. No LDS, no barriers.
// Lane l owns gates l (i/f) and 64+l (g/o). h lives in lanes 0..31, broadcast
// via __shfl. Next step's gates_x/done prefetched before the dot chain.
// ---------------------------------------------------------------------------
__device__ __forceinline__ float sigmoidf_(float v) {
    return 1.0f / (1.0f + __expf(-v));
}
__device__ __forceinline__ float tanh_safe(float v) {
    const float av = fabsf(v);
    const float e = __expf(-2.0f * av);
    const float r = (1.0f - e) / (1.0f + e);
    return v < 0.f ? -r : r;
}

__global__ __launch_bounds__(64) void k_lstm(const float* __restrict__ gates_x,
                                             const float* __restrict__ done,
                                             const float* __restrict__ h0,
                                             const float* __restrict__ c0,
                                             const float* __restrict__ w_hh,
                                             const float* __restrict__ b_ih,
                                             const float* __restrict__ b_hh,
                                             const float* __restrict__ critic_w,
                                             const float* __restrict__ critic_b,
                                             float* __restrict__ out) {
    const int b = blockIdx.x;
    const int l = threadIdx.x;        // 0..63
    const int g0 = l;
    const int g1 = 64 + l;

    float wr0[H_DIM], wr1[H_DIM];
#pragma unroll
    for (int k = 0; k < H_DIM; ++k) {
        wr0[k] = w_hh[g0 * H_DIM + k];
        wr1[k] = w_hh[g1 * H_DIM + k];
    }
    const float bs0 = b_ih[g0] + b_hh[g0];
    const float bs1 = b_ih[g1] + b_hh[g1];

    float h_reg = (l < H_DIM) ? h0[b * H_DIM + l] : 0.f;
    float c_reg = (l < H_DIM) ? c0[b * H_DIM + l] : 0.f;
    const float cw = (l < H_DIM) ? critic_w[l] : 0.f;
    const float cb = critic_b[0];

    // prefetch step 0
    float nx0 = gates_x[(size_t)b * G4H + g0];
    float nx1 = gates_x[(size_t)b * G4H + g1];
    float nd  = done[b];

    for (int step = 0; step < T_STEPS; ++step) {
        const float gx0 = nx0, gx1 = nx1, dv = nd;
        // prefetch step+1 (clamped; redundant refetch on last step is harmless)
        const int ns = (step + 1 < T_STEPS) ? step + 1 : step;
        const size_t nb = (size_t)(ns * B_ENVS + b) * G4H;
        nx0 = gates_x[nb + g0];
        nx1 = gates_x[nb + g1];
        nd  = done[ns * B_ENVS + b];

        const float keep = 1.0f - dv;
        float d0 = 0.f, d1 = 0.f;
#pragma unroll
        for (int k = 0; k < H_DIM; ++k) {
            const float hk = __shfl(h_reg, k);
            d0 = fmaf(hk, wr0[k], d0);
            d1 = fmaf(hk, wr1[k], d1);
        }
        const float pre0 = gx0 + bs0 + keep * d0;
        const float pre1 = gx1 + bs1 + keep * d1;

        const float act0 = sigmoidf_(pre0);                    // i (l<32) / f (l>=32)
        const float act1 = (l < 32) ? tanh_safe(pre1)          // g
                                    : sigmoidf_(pre1);         // o
        const float fv = __shfl_xor(act0, 32);
        const float ov = __shfl_xor(act1, 32);

        c_reg = fmaf(fv, keep * c_reg, act0 * act1);           // valid for l<32
        h_reg = ov * tanh_safe(c_reg);
        float val = h_reg * cw;                                // cw=0 for l>=32
#pragma unroll
        for (int off = 1; off < 32; off <<= 1) val += __shfl_xor(val, off);
        if (l == 0) out[step * B_ENVS + b] = val + cb;
    }
}

// ---------------------------------------------------------------------------
extern "C" void kernel_launch(void* const* d_in, const int* in_sizes, int n_in,
                              void* d_out, int out_size, void* d_ws, size_t ws_size,
                              hipStream_t stream) {
    const float* x    = (const float*)d_in[0];
    const float* done = (const float*)d_in[1];
    const int* mask   = (const int*)d_in[2];
    const float* h0   = (const float*)d_in[3];
    const float* c0   = (const float*)d_in[4];
    const float* ipw  = (const float*)d_in[5];
    const float* opw  = (const float*)d_in[6];
    const float* w_ih = (const float*)d_in[7];
    const float* w_hh = (const float*)d_in[8];
    const float* b_ih = (const float*)d_in[9];
    const float* b_hh = (const float*)d_in[10];
    const float* cw   = (const float*)d_in[11];
    const float* cb   = (const float*)d_in[12];
    float* out = (float*)d_out;

    char* ws = (char*)d_ws;
    __bf16* Mtb = (__bf16*)(ws);                    // 128 KB
    float* R    = (float*)(ws + (128 * 1024));      // 128 KB
    float* Q    = (float*)(ws + (256 * 1024));      // 128 KB
    float* gx   = (float*)(ws + (384 * 1024));      // 4 MB

    k_precompute_M<<<256, 256, 0, stream>>>(ipw, Mtb);
    k_precompute_R<<<128, 256, 0, stream>>>(w_ih, opw, R);
    k_precompute_Q<<<128, 256, 0, stream>>>(ipw, R, Q);
    k_attn<<<N_SEQ, 1024, 0, stream>>>(x, mask, Mtb, Q, gx);
    k_lstm<<<B_ENVS, 64, 0, stream>>>(gx, done, h0, c0, w_hh, b_ih, b_hh, cw, cb, out);
}